// Round 5
// baseline (20974.232 us; speedup 1.0000x reference)
//
#include <hip/hip_runtime.h>
#include <hip/hip_bf16.h>

// ---------------------------------------------------------------------------
// BigBird-roberta-base forward (B=1, S=2048, D=768, F=3072, V=50358, L=12,
// H=12, HD=64, BS=64, NB=32, R=3). Split-bf16 (hi+lo) MFMA everywhere ->
// ~f32 accuracy for GEMMs AND attention.
// ---------------------------------------------------------------------------

#define S_LEN 2048
#define DMODEL 768
#define FFDIM 3072
#define VOCAB 50358
#define NLAYER 12
#define NHEAD 12
#define HEADD 64
#define NB 32
#define NKB 8

typedef __attribute__((ext_vector_type(8))) short bfrag8;   // 8 bf16 (4 VGPRs)
typedef __attribute__((ext_vector_type(4))) float facc4;    // 4 f32 acc

__device__ __forceinline__ unsigned short f2bf(float f) {
  unsigned int u = __builtin_bit_cast(unsigned int, f);
  u += 0x7fffu + ((u >> 16) & 1u);            // round-to-nearest-even
  return (unsigned short)(u >> 16);
}
__device__ __forceinline__ float bf2f(unsigned short h) {
  unsigned int u = ((unsigned int)h) << 16;
  return __builtin_bit_cast(float, u);
}

#define MFMA16(a, b, c) __builtin_amdgcn_mfma_f32_16x16x32_bf16((a), (b), (c), 0, 0, 0)

// ---------------------------------------------------------------------------
// numpy RNG replication: SeedSequence(0) -> PCG64 -> Generator.choice
// Floyd's algorithm + post-shuffle (Fisher-Yates, 2 extra draws/block).
// ---------------------------------------------------------------------------
struct Pcg {
  unsigned long long hi, lo, inc_hi, inc_lo;
  int has32; unsigned int buf32;
};

__device__ __forceinline__ void pcg_step(Pcg& p) {
  const unsigned long long MH = 0x2360ed051fc65da4ull;
  const unsigned long long ML = 0x4385df649fccf645ull;
  unsigned long long rl = p.lo * ML;
  unsigned long long rh = __umul64hi(p.lo, ML) + p.lo * MH + p.hi * ML;
  unsigned long long nl = rl + p.inc_lo;
  unsigned long long nh = rh + p.inc_hi + (nl < rl ? 1ull : 0ull);
  p.lo = nl; p.hi = nh;
}
__device__ __forceinline__ unsigned long long pcg_next64(Pcg& p) {
  pcg_step(p);
  unsigned int rot = (unsigned int)(p.hi >> 58);
  unsigned long long x = p.hi ^ p.lo;
  return (x >> rot) | (x << ((64u - rot) & 63u));
}
__device__ __forceinline__ unsigned int pcg_next32(Pcg& p) {
  if (p.has32) { p.has32 = 0; return p.buf32; }
  unsigned long long n = pcg_next64(p);
  p.has32 = 1; p.buf32 = (unsigned int)(n >> 32);
  return (unsigned int)n;                           // low half first
}
__device__ __forceinline__ unsigned int lemire32(Pcg& p, unsigned int rng) {
  unsigned int rng_excl = rng + 1u;
  unsigned long long m = (unsigned long long)pcg_next32(p) * (unsigned long long)rng_excl;
  unsigned int leftover = (unsigned int)m;
  if (leftover < rng_excl) {
    unsigned int threshold = (0xffffffffu - rng) % rng_excl;
    while (leftover < threshold) {
      m = (unsigned long long)pcg_next32(p) * (unsigned long long)rng_excl;
      leftover = (unsigned int)m;
    }
  }
  return (unsigned int)(m >> 32);
}

__global__ void blockmap_kernel(int* __restrict__ blk_idx, float* __restrict__ dedup) {
  if (threadIdx.x != 0 || blockIdx.x != 0) return;
  unsigned int pool[4];
  unsigned int hc = 0x43b0d7e5u;   // INIT_A
  auto ss_hash = [&hc](unsigned int val) {
    val ^= hc; hc *= 0x931e8875u; val *= hc; val ^= val >> 16; return val;
  };
  auto ss_mix = [](unsigned int x, unsigned int y) {
    unsigned int r = 0xca01f9ddu * x - 0x4973f715u * y;   // MIX_MULT_L*x - MIX_MULT_R*y
    r ^= r >> 16; return r;
  };
  for (int i = 0; i < 4; ++i) pool[i] = ss_hash(0u);
  for (int s = 0; s < 4; ++s)
    for (int d = 0; d < 4; ++d)
      if (s != d) pool[d] = ss_mix(pool[d], ss_hash(pool[s]));
  unsigned int st32[8];
  unsigned int hb = 0x8b51f9ddu;   // INIT_B
  for (int i = 0; i < 8; ++i) {
    unsigned int dv = pool[i & 3];
    dv ^= hb; hb *= 0x58f38dedu; dv *= hb; dv ^= dv >> 16;   // MULT_B
    st32[i] = dv;
  }
  unsigned long long sd[4];
  for (int i = 0; i < 4; ++i)
    sd[i] = (unsigned long long)st32[2*i] | ((unsigned long long)st32[2*i+1] << 32);
  Pcg p;
  p.inc_hi = (sd[2] << 1) | (sd[3] >> 63);
  p.inc_lo = (sd[3] << 1) | 1ull;
  p.hi = 0ull; p.lo = 0ull;
  pcg_step(p);
  unsigned long long ol = p.lo;
  p.lo = ol + sd[1];
  p.hi = p.hi + sd[0] + (p.lo < ol ? 1ull : 0ull);
  pcg_step(p);
  p.has32 = 0; p.buf32 = 0;

  for (int i = 0; i < NB; ++i) {
    int lst[8];
    lst[0] = 0; lst[1] = NB - 1;
    lst[2] = (i > 0) ? i - 1 : 0;
    lst[3] = i;
    lst[4] = (i + 1 < NB - 1) ? i + 1 : NB - 1;
    bool excl[NB];
    for (int c = 0; c < NB; ++c) excl[c] = false;
    for (int j = 0; j < 5; ++j) excl[lst[j]] = true;
    int cand[NB], n = 0;
    for (int c = 0; c < NB; ++c) if (!excl[c]) cand[n++] = c;
    // Floyd's algorithm, size=3, hash set of 4 (mask=3)
    long long idx[3];
    unsigned long long hs[4] = {~0ull, ~0ull, ~0ull, ~0ull};
    for (int tI = 0; tI < 3; ++tI) {
      unsigned long long j = (unsigned long long)(n - 3 + tI);
      unsigned long long val = (unsigned long long)lemire32(p, (unsigned int)j);
      unsigned long long loc = val & 3ull;
      while (hs[loc] != ~0ull && hs[loc] != val) loc = (loc + 1ull) & 3ull;
      if (hs[loc] == ~0ull) { hs[loc] = val; idx[tI] = (long long)val; }
      else {
        loc = j & 3ull;
        while (hs[loc] != ~0ull) loc = (loc + 1ull) & 3ull;
        hs[loc] = j; idx[tI] = (long long)j;
      }
    }
    // Generator.choice(..., shuffle=True): Fisher-Yates on idx (2 draws)
    for (int fi = 2; fi >= 1; --fi) {
      int fj = (int)lemire32(p, (unsigned int)fi);
      long long tmp = idx[fi]; idx[fi] = idx[fj]; idx[fj] = tmp;
    }
    lst[5] = cand[idx[0]]; lst[6] = cand[idx[1]]; lst[7] = cand[idx[2]];

    unsigned int seen = 0u;
    for (int j = 0; j < 8; ++j) {
      blk_idx[i*8 + j] = lst[j];
      dedup[i*8 + j] = ((seen >> lst[j]) & 1u) ? 0.0f : 1.0f;
      seen |= (1u << lst[j]);
    }
  }
}

// ---------------------------------------------------------------------------
// LayerNorm helpers
// ---------------------------------------------------------------------------
__device__ __forceinline__ float block_sum256(float v, float* red) {
  for (int off = 32; off > 0; off >>= 1) v += __shfl_down(v, off);
  int wv = threadIdx.x >> 6;
  if ((threadIdx.x & 63) == 0) red[wv] = v;
  __syncthreads();
  float r = red[0] + red[1] + red[2] + red[3];
  __syncthreads();
  return r;
}

__global__ void embed_ln_kernel(const int* __restrict__ ids, const int* __restrict__ tts,
                                const float* __restrict__ we, const float* __restrict__ pe,
                                const float* __restrict__ te, const float* __restrict__ lns,
                                const float* __restrict__ lnb, float* __restrict__ x) {
  __shared__ float red[4];
  int row = blockIdx.x, t = threadIdx.x;
  int id = ids[row], ty = tts[row];
  float e[3]; float s = 0.0f;
  for (int j = 0; j < 3; ++j) {
    int d = t + 256*j;
    e[j] = we[(size_t)id*DMODEL + d] + pe[(size_t)row*DMODEL + d] + te[(size_t)ty*DMODEL + d];
    s += e[j];
  }
  float mean = block_sum256(s, red) * (1.0f/768.0f);
  float vs = 0.0f;
  for (int j = 0; j < 3; ++j) { float dd = e[j] - mean; vs += dd*dd; }
  float var = block_sum256(vs, red) * (1.0f/768.0f);
  float inv = rsqrtf(var + 1e-12f);
  for (int j = 0; j < 3; ++j) {
    int d = t + 256*j;
    x[(size_t)row*DMODEL + d] = (e[j] - mean) * inv * lns[d] + lnb[d];
  }
}

__global__ void resln_kernel(float* __restrict__ x, const float* __restrict__ a,
                             const float* __restrict__ lns, const float* __restrict__ lnb) {
  __shared__ float red[4];
  int row = blockIdx.x, t = threadIdx.x;
  float e[3]; float s = 0.0f;
  for (int j = 0; j < 3; ++j) {
    int d = t + 256*j;
    e[j] = x[(size_t)row*DMODEL + d] + a[(size_t)row*DMODEL + d];
    s += e[j];
  }
  float mean = block_sum256(s, red) * (1.0f/768.0f);
  float vs = 0.0f;
  for (int j = 0; j < 3; ++j) { float dd = e[j] - mean; vs += dd*dd; }
  float var = block_sum256(vs, red) * (1.0f/768.0f);
  float inv = rsqrtf(var + 1e-12f);
  for (int j = 0; j < 3; ++j) {
    int d = t + 256*j;
    x[(size_t)row*DMODEL + d] = (e[j] - mean) * inv * lns[d] + lnb[d];
  }
}

// ---------------------------------------------------------------------------
// Split-precision GEMM: C[M,N] = act(A[M,K] @ W[K,N] + bias[N])
// acc += ah*bh + ah*bl + al*bh  (~f32 accurate)
// M % 128 == 0, K % 32 == 0; N arbitrary. act: 0=none, 1=gelu(tanh)
// ---------------------------------------------------------------------------
__global__ __launch_bounds__(256) void gemm_kernel(
    const float* __restrict__ A, const float* __restrict__ W,
    const float* __restrict__ bias, float* __restrict__ C,
    int M, int N, int K, int act) {
  __shared__ alignas(16) unsigned short Ah[128][32];
  __shared__ alignas(16) unsigned short Al[128][32];
  __shared__ alignas(16) unsigned short Bh[128][32];   // [n][k]
  __shared__ alignas(16) unsigned short Bl[128][32];
  int t = threadIdx.x;
  int n0 = blockIdx.x * 128, m0 = blockIdx.y * 128;
  int wave = t >> 6, lane = t & 63, l16 = lane & 15, lk = lane >> 4;
  int wr = wave >> 1, wc = wave & 1;
  facc4 acc[4][4];
  for (int mi = 0; mi < 4; ++mi)
    for (int ni = 0; ni < 4; ++ni)
      acc[mi][ni] = (facc4){0.f, 0.f, 0.f, 0.f};
  const bool nfull = (n0 + 128 <= N);
  const int arow = t >> 3, acol = (t & 7) * 4;
  const int bk0 = t >> 5, bnc = (t & 31) * 4;

  for (int k0 = 0; k0 < K; k0 += 32) {
    #pragma unroll
    for (int j = 0; j < 4; ++j) {
      const float4 vv = *reinterpret_cast<const float4*>(
          A + (size_t)(m0 + arow + 32*j) * K + k0 + acol);
      ushort4 h4, l4;
      h4.x = f2bf(vv.x); l4.x = f2bf(vv.x - bf2f(h4.x));
      h4.y = f2bf(vv.y); l4.y = f2bf(vv.y - bf2f(h4.y));
      h4.z = f2bf(vv.z); l4.z = f2bf(vv.z - bf2f(h4.z));
      h4.w = f2bf(vv.w); l4.w = f2bf(vv.w - bf2f(h4.w));
      *reinterpret_cast<ushort4*>(&Ah[arow + 32*j][acol]) = h4;
      *reinterpret_cast<ushort4*>(&Al[arow + 32*j][acol]) = l4;
    }
    #pragma unroll
    for (int j = 0; j < 4; ++j) {
      int kk = bk0 + 8*j;
      float4 vv;
      if (nfull) {
        vv = *reinterpret_cast<const float4*>(W + (size_t)(k0 + kk) * N + n0 + bnc);
      } else {
        float tv[4];
        for (int q = 0; q < 4; ++q) {
          int n = n0 + bnc + q;
          tv[q] = (n < N) ? W[(size_t)(k0 + kk) * N + n] : 0.0f;
        }
        vv.x = tv[0]; vv.y = tv[1]; vv.z = tv[2]; vv.w = tv[3];
      }
      unsigned short h;
      h = f2bf(vv.x); Bh[bnc + 0][kk] = h; Bl[bnc + 0][kk] = f2bf(vv.x - bf2f(h));
      h = f2bf(vv.y); Bh[bnc + 1][kk] = h; Bl[bnc + 1][kk] = f2bf(vv.y - bf2f(h));
      h = f2bf(vv.z); Bh[bnc + 2][kk] = h; Bl[bnc + 2][kk] = f2bf(vv.z - bf2f(h));
      h = f2bf(vv.w); Bh[bnc + 3][kk] = h; Bl[bnc + 3][kk] = f2bf(vv.w - bf2f(h));
    }
    __syncthreads();
    bfrag8 afh[4], afl[4], bfh[4], bfl[4];
    #pragma unroll
    for (int mi = 0; mi < 4; ++mi) {
      afh[mi] = *reinterpret_cast<const bfrag8*>(&Ah[wr*64 + mi*16 + l16][lk*8]);
      afl[mi] = *reinterpret_cast<const bfrag8*>(&Al[wr*64 + mi*16 + l16][lk*8]);
    }
    #pragma unroll
    for (int ni = 0; ni < 4; ++ni) {
      bfh[ni] = *reinterpret_cast<const bfrag8*>(&Bh[wc*64 + ni*16 + l16][lk*8]);
      bfl[ni] = *reinterpret_cast<const bfrag8*>(&Bl[wc*64 + ni*16 + l16][lk*8]);
    }
    #pragma unroll
    for (int mi = 0; mi < 4; ++mi)
      #pragma unroll
      for (int ni = 0; ni < 4; ++ni) {
        acc[mi][ni] = MFMA16(afh[mi], bfh[ni], acc[mi][ni]);
        acc[mi][ni] = MFMA16(afh[mi], bfl[ni], acc[mi][ni]);
        acc[mi][ni] = MFMA16(afl[mi], bfh[ni], acc[mi][ni]);
      }
    __syncthreads();
  }

  for (int mi = 0; mi < 4; ++mi)
    for (int ni = 0; ni < 4; ++ni) {
      int col = n0 + wc*64 + ni*16 + l16;
      if (col >= N) continue;
      float bv = bias[col];
      for (int r = 0; r < 4; ++r) {
        int row = m0 + wr*64 + mi*16 + lk*4 + r;
        float val = acc[mi][ni][r] + bv;
        if (act == 1) {
          float xx = val;
          val = 0.5f * xx * (1.0f + tanhf(0.7978845608028654f * (xx + 0.044715f * xx * xx * xx)));
        }
        C[(size_t)row * N + col] = val;
      }
    }
}

// ---------------------------------------------------------------------------
// Split staging: 64x64 f32 tile -> (hi,lo) bf16 LDS pair, direct / transposed
// ---------------------------------------------------------------------------
__device__ __forceinline__ void stage_split(unsigned short (*dsth)[64], unsigned short (*dstl)[64],
                                            const float* __restrict__ src, int ld, int t) {
  int row = t >> 2, colb = (t & 3) * 16;
  const float* sp = src + (size_t)row * ld + colb;
  #pragma unroll
  for (int j = 0; j < 4; ++j) {
    float4 vv = *reinterpret_cast<const float4*>(sp + j*4);
    ushort4 h4, l4;
    h4.x = f2bf(vv.x); l4.x = f2bf(vv.x - bf2f(h4.x));
    h4.y = f2bf(vv.y); l4.y = f2bf(vv.y - bf2f(h4.y));
    h4.z = f2bf(vv.z); l4.z = f2bf(vv.z - bf2f(h4.z));
    h4.w = f2bf(vv.w); l4.w = f2bf(vv.w - bf2f(h4.w));
    *reinterpret_cast<ushort4*>(&dsth[row][colb + j*4]) = h4;
    *reinterpret_cast<ushort4*>(&dstl[row][colb + j*4]) = l4;
  }
}
__device__ __forceinline__ void stage_splitT(unsigned short (*dsth)[64], unsigned short (*dstl)[64],
                                             const float* __restrict__ src, int ld, int t) {
  int row = t >> 2, colb = (t & 3) * 16;
  const float* sp = src + (size_t)row * ld + colb;
  #pragma unroll
  for (int j = 0; j < 4; ++j) {
    float4 vv = *reinterpret_cast<const float4*>(sp + j*4);
    int c = colb + j*4;
    unsigned short h;
    h = f2bf(vv.x); dsth[c+0][row] = h; dstl[c+0][row] = f2bf(vv.x - bf2f(h));
    h = f2bf(vv.y); dsth[c+1][row] = h; dstl[c+1][row] = f2bf(vv.y - bf2f(h));
    h = f2bf(vv.z); dsth[c+2][row] = h; dstl[c+2][row] = f2bf(vv.z - bf2f(h));
    h = f2bf(vv.w); dsth[c+3][row] = h; dstl[c+3][row] = f2bf(vv.w - bf2f(h));
  }
}

__device__ __forceinline__ void unpack_pair(int4 u0, int4 u1, bfrag8& hi, bfrag8& lo) {
  int a[8] = {u0.x, u0.y, u0.z, u0.w, u1.x, u1.y, u1.z, u1.w};
  #pragma unroll
  for (int j = 0; j < 8; ++j) {
    hi[j] = (short)((unsigned)a[j] & 0xffffu);
    lo[j] = (short)((unsigned)a[j] >> 16);
  }
}

// ---------------------------------------------------------------------------
// Sparse BigBird attention, two-pass recompute, split precision throughout.
// One block per (query block, head).
// ---------------------------------------------------------------------------
__global__ __launch_bounds__(256) void sparse_attn_kernel(
    const float* __restrict__ q, const float* __restrict__ k, const float* __restrict__ v,
    const int* __restrict__ blk_idx, const float* __restrict__ dedup,
    const int* __restrict__ amask, float* __restrict__ ctx) {
  __shared__ alignas(16) unsigned short Qh[64][64], Ql[64][64];
  __shared__ alignas(16) unsigned short KVh[64][64], KVl[64][64];
  __shared__ alignas(16) unsigned int Pt[64][64];
  int qi = blockIdx.x, h = blockIdx.y;
  int t = threadIdx.x, wave = t >> 6, lane = t & 63, l16 = lane & 15, lk = lane >> 4;

  stage_split(Qh, Ql, q + (size_t)(qi*64)*DMODEL + h*HEADD, DMODEL, t);
  __syncthreads();
  const bfrag8 qh0 = *reinterpret_cast<const bfrag8*>(&Qh[wave*16 + l16][lk*8]);
  const bfrag8 qh1 = *reinterpret_cast<const bfrag8*>(&Qh[wave*16 + l16][32 + lk*8]);
  const bfrag8 ql0 = *reinterpret_cast<const bfrag8*>(&Ql[wave*16 + l16][lk*8]);
  const bfrag8 ql1 = *reinterpret_cast<const bfrag8*>(&Ql[wave*16 + l16][32 + lk*8]);

  float mrow[4] = {-3.0e38f, -3.0e38f, -3.0e38f, -3.0e38f};
  float lrow[4] = {0.f, 0.f, 0.f, 0.f};

  // ---- pass 1: online row max/sum (no score storage) ----
  for (int kb = 0; kb < NKB; ++kb) {
    int b = blk_idx[qi*NKB + kb];
    float dd = dedup[qi*NKB + kb];
    __syncthreads();
    stage_split(KVh, KVl, k + (size_t)(b*64)*DMODEL + h*HEADD, DMODEL, t);
    __syncthreads();
    float s[4][4];
    #pragma unroll
    for (int ni = 0; ni < 4; ++ni) {
      bfrag8 bh0 = *reinterpret_cast<const bfrag8*>(&KVh[ni*16 + l16][lk*8]);
      bfrag8 bl0 = *reinterpret_cast<const bfrag8*>(&KVl[ni*16 + l16][lk*8]);
      bfrag8 bh1 = *reinterpret_cast<const bfrag8*>(&KVh[ni*16 + l16][32 + lk*8]);
      bfrag8 bl1 = *reinterpret_cast<const bfrag8*>(&KVl[ni*16 + l16][32 + lk*8]);
      facc4 sa = (facc4){0.f, 0.f, 0.f, 0.f};
      sa = MFMA16(qh0, bh0, sa); sa = MFMA16(qh0, bl0, sa); sa = MFMA16(ql0, bh0, sa);
      sa = MFMA16(qh1, bh1, sa); sa = MFMA16(qh1, bl1, sa); sa = MFMA16(ql1, bh1, sa);
      int colk = ni*16 + l16;
      float m = (float)amask[b*64 + colk] * dd;
      float addm = (1.0f - m) * (-1.0e9f);
      #pragma unroll
      for (int r = 0; r < 4; ++r) s[ni][r] = sa[r] * 0.125f + addm;
    }
    #pragma unroll
    for (int r = 0; r < 4; ++r) {
      float tm = fmaxf(fmaxf(s[0][r], s[1][r]), fmaxf(s[2][r], s[3][r]));
      tm = fmaxf(tm, __shfl_xor(tm, 1));
      tm = fmaxf(tm, __shfl_xor(tm, 2));
      tm = fmaxf(tm, __shfl_xor(tm, 4));
      tm = fmaxf(tm, __shfl_xor(tm, 8));
      float mn = fmaxf(mrow[r], tm);
      float ps = expf(s[0][r]-mn) + expf(s[1][r]-mn) + expf(s[2][r]-mn) + expf(s[3][r]-mn);
      ps += __shfl_xor(ps, 1);
      ps += __shfl_xor(ps, 2);
      ps += __shfl_xor(ps, 4);
      ps += __shfl_xor(ps, 8);
      lrow[r] = lrow[r] * expf(mrow[r] - mn) + ps;
      mrow[r] = mn;
    }
  }
  float invl[4];
  #pragma unroll
  for (int r = 0; r < 4; ++r) invl[r] = 1.0f / lrow[r];

  // ---- pass 2: recompute scores, P = exp(s-m)/l as (hi,lo) pairs, PV ----
  facc4 o[4];
  #pragma unroll
  for (int ni = 0; ni < 4; ++ni) o[ni] = (facc4){0.f, 0.f, 0.f, 0.f};

  for (int kb = 0; kb < NKB; ++kb) {
    int b = blk_idx[qi*NKB + kb];
    float dd = dedup[qi*NKB + kb];
    __syncthreads();
    stage_split(KVh, KVl, k + (size_t)(b*64)*DMODEL + h*HEADD, DMODEL, t);
    __syncthreads();
    #pragma unroll
    for (int ni = 0; ni < 4; ++ni) {
      bfrag8 bh0 = *reinterpret_cast<const bfrag8*>(&KVh[ni*16 + l16][lk*8]);
      bfrag8 bl0 = *reinterpret_cast<const bfrag8*>(&KVl[ni*16 + l16][lk*8]);
      bfrag8 bh1 = *reinterpret_cast<const bfrag8*>(&KVh[ni*16 + l16][32 + lk*8]);
      bfrag8 bl1 = *reinterpret_cast<const bfrag8*>(&KVl[ni*16 + l16][32 + lk*8]);
      facc4 sa = (facc4){0.f, 0.f, 0.f, 0.f};
      sa = MFMA16(qh0, bh0, sa); sa = MFMA16(qh0, bl0, sa); sa = MFMA16(ql0, bh0, sa);
      sa = MFMA16(qh1, bh1, sa); sa = MFMA16(qh1, bl1, sa); sa = MFMA16(ql1, bh1, sa);
      int colk = ni*16 + l16;
      float m = (float)amask[b*64 + colk] * dd;
      float addm = (1.0f - m) * (-1.0e9f);
      #pragma unroll
      for (int r = 0; r < 4; ++r) {
        float sv = sa[r] * 0.125f + addm;
        float p = expf(sv - mrow[r]) * invl[r];
        unsigned short hi = f2bf(p);
        unsigned short lo = f2bf(p - bf2f(hi));
        Pt[wave*16 + lk*4 + r][colk] = (unsigned)hi | ((unsigned)lo << 16);
      }
    }
    __syncthreads();
    stage_splitT(KVh, KVl, v + (size_t)(b*64)*DMODEL + h*HEADD, DMODEL, t);  // [dim][key]
    __syncthreads();
    #pragma unroll
    for (int kc = 0; kc < 2; ++kc) {
      int4 u0 = *reinterpret_cast<const int4*>(&Pt[wave*16 + l16][kc*32 + lk*8]);
      int4 u1 = *reinterpret_cast<const int4*>(&Pt[wave*16 + l16][kc*32 + lk*8 + 4]);
      bfrag8 ph, pl;
      unpack_pair(u0, u1, ph, pl);
      #pragma unroll
      for (int ni = 0; ni < 4; ++ni) {
        bfrag8 vh = *reinterpret_cast<const bfrag8*>(&KVh[ni*16 + l16][kc*32 + lk*8]);
        bfrag8 vl = *reinterpret_cast<const bfrag8*>(&KVl[ni*16 + l16][kc*32 + lk*8]);
        o[ni] = MFMA16(ph, vh, o[ni]);
        o[ni] = MFMA16(ph, vl, o[ni]);
        o[ni] = MFMA16(pl, vh, o[ni]);
      }
    }
  }
  #pragma unroll
  for (int ni = 0; ni < 4; ++ni)
    #pragma unroll
    for (int r = 0; r < 4; ++r) {
      int row = qi*64 + wave*16 + lk*4 + r;
      int col = h*HEADD + ni*16 + l16;
      ctx[(size_t)row*DMODEL + col] = o[ni][r];
    }
}

// ---------------------------------------------------------------------------
// Global attention for query blocks 0 and 31, split precision.
// Scores/probs in f32 workspace. One block per (g, head).
// ---------------------------------------------------------------------------
__global__ __launch_bounds__(256) void global_attn_kernel(
    const float* __restrict__ q, const float* __restrict__ k, const float* __restrict__ v,
    const int* __restrict__ amask, float* __restrict__ gsc, float* __restrict__ ctx) {
  __shared__ alignas(16) unsigned short Qh[64][64], Ql[64][64];
  __shared__ alignas(16) unsigned short KVh[64][64], KVl[64][64];
  __shared__ alignas(16) unsigned int Pt[64][64];
  int g = blockIdx.x, h = blockIdx.y;
  int qblk = (g == 0) ? 0 : (NB - 1);
  float* sc = gsc + (size_t)(g*NHEAD + h) * 64 * S_LEN;
  int t = threadIdx.x, wave = t >> 6, lane = t & 63, l16 = lane & 15, lk = lane >> 4;

  stage_split(Qh, Ql, q + (size_t)(qblk*64)*DMODEL + h*HEADD, DMODEL, t);
  __syncthreads();
  const bfrag8 qh0 = *reinterpret_cast<const bfrag8*>(&Qh[wave*16 + l16][lk*8]);
  const bfrag8 qh1 = *reinterpret_cast<const bfrag8*>(&Qh[wave*16 + l16][32 + lk*8]);
  const bfrag8 ql0 = *reinterpret_cast<const bfrag8*>(&Ql[wave*16 + l16][lk*8]);
  const bfrag8 ql1 = *reinterpret_cast<const bfrag8*>(&Ql[wave*16 + l16][32 + lk*8]);

  for (int kb = 0; kb < NB; ++kb) {
    __syncthreads();
    stage_split(KVh, KVl, k + (size_t)(kb*64)*DMODEL + h*HEADD, DMODEL, t);
    __syncthreads();
    #pragma unroll
    for (int ni = 0; ni < 4; ++ni) {
      bfrag8 bh0 = *reinterpret_cast<const bfrag8*>(&KVh[ni*16 + l16][lk*8]);
      bfrag8 bl0 = *reinterpret_cast<const bfrag8*>(&KVl[ni*16 + l16][lk*8]);
      bfrag8 bh1 = *reinterpret_cast<const bfrag8*>(&KVh[ni*16 + l16][32 + lk*8]);
      bfrag8 bl1 = *reinterpret_cast<const bfrag8*>(&KVl[ni*16 + l16][32 + lk*8]);
      facc4 sa = (facc4){0.f, 0.f, 0.f, 0.f};
      sa = MFMA16(qh0, bh0, sa); sa = MFMA16(qh0, bl0, sa); sa = MFMA16(ql0, bh0, sa);
      sa = MFMA16(qh1, bh1, sa); sa = MFMA16(qh1, bl1, sa); sa = MFMA16(ql1, bh1, sa);
      int gcol = kb*64 + ni*16 + l16;
      float addm = (1.0f - (float)amask[gcol]) * (-1.0e9f);
      #pragma unroll
      for (int r = 0; r < 4; ++r) {
        int qr = wave*16 + lk*4 + r;
        sc[(size_t)qr * S_LEN + gcol] = sa[r] * 0.125f + addm;
      }
    }
  }
  __syncthreads();
  {
    int row = t >> 2, part = t & 3;
    float mx = -3.0e38f;
    for (int j = 0; j < 512; ++j) mx = fmaxf(mx, sc[(size_t)row*S_LEN + part + 4*j]);
    mx = fmaxf(mx, __shfl_xor(mx, 1));
    mx = fmaxf(mx, __shfl_xor(mx, 2));
    float sm = 0.0f;
    for (int j = 0; j < 512; ++j) sm += expf(sc[(size_t)row*S_LEN + part + 4*j] - mx);
    sm += __shfl_xor(sm, 1);
    sm += __shfl_xor(sm, 2);
    float inv = 1.0f / sm;
    for (int j = 0; j < 512; ++j) {
      size_t idx = (size_t)row*S_LEN + part + 4*j;
      sc[idx] = expf(sc[idx] - mx) * inv;
    }
  }
  facc4 o[4];
  #pragma unroll
  for (int ni = 0; ni < 4; ++ni) o[ni] = (facc4){0.f, 0.f, 0.f, 0.f};
  for (int kb = 0; kb < NB; ++kb) {
    __syncthreads();
    stage_splitT(KVh, KVl, v + (size_t)(kb*64)*DMODEL + h*HEADD, DMODEL, t);
    {
      int row = t >> 2, colb = (t & 3) * 16;
      const float* sp = sc + (size_t)row * S_LEN + kb*64 + colb;
      #pragma unroll
      for (int j = 0; j < 4; ++j) {
        float4 vv = *reinterpret_cast<const float4*>(sp + j*4);
        int c = colb + j*4;
        unsigned short hi, lo;
        hi = f2bf(vv.x); lo = f2bf(vv.x - bf2f(hi)); Pt[row][c+0] = (unsigned)hi | ((unsigned)lo << 16);
        hi = f2bf(vv.y); lo = f2bf(vv.y - bf2f(hi)); Pt[row][c+1] = (unsigned)hi | ((unsigned)lo << 16);
        hi = f2bf(vv.z); lo = f2bf(vv.z - bf2f(hi)); Pt[row][c+2] = (unsigned)hi | ((unsigned)lo << 16);
        hi = f2bf(vv.w); lo = f2bf(vv.w - bf2f(hi)); Pt[row][c+3] = (unsigned)hi | ((unsigned)lo << 16);
      }
    }
    __syncthreads();
    #pragma unroll
    for (int kc = 0; kc < 2; ++kc) {
      int4 u0 = *reinterpret_cast<const int4*>(&Pt[wave*16 + l16][kc*32 + lk*8]);
      int4 u1 = *reinterpret_cast<const int4*>(&Pt[wave*16 + l16][kc*32 + lk*8 + 4]);
      bfrag8 ph, pl;
      unpack_pair(u0, u1, ph, pl);
      #pragma unroll
      for (int ni = 0; ni < 4; ++ni) {
        bfrag8 vh = *reinterpret_cast<const bfrag8*>(&KVh[ni*16 + l16][kc*32 + lk*8]);
        bfrag8 vl = *reinterpret_cast<const bfrag8*>(&KVl[ni*16 + l16][kc*32 + lk*8]);
        o[ni] = MFMA16(ph, vh, o[ni]);
        o[ni] = MFMA16(ph, vl, o[ni]);
        o[ni] = MFMA16(pl, vh, o[ni]);
      }
    }
  }
  #pragma unroll
  for (int ni = 0; ni < 4; ++ni)
    #pragma unroll
    for (int r = 0; r < 4; ++r) {
      int row = qblk*64 + wave*16 + lk*4 + r;
      int col = h*HEADD + ni*16 + l16;
      ctx[(size_t)row*DMODEL + col] = o[ni][r];
    }
}

// ---------------------------------------------------------------------------
// Launch
// ---------------------------------------------------------------------------
static inline void launch_gemm(const float* A, const float* W, const float* bias,
                               float* C, int M, int N, int K, int act, hipStream_t s) {
  dim3 grid((N + 127) / 128, M / 128);
  gemm_kernel<<<grid, 256, 0, s>>>(A, W, bias, C, M, N, K, act);
}

extern "C" void kernel_launch(void* const* d_in, const int* in_sizes, int n_in,
                              void* d_out, int out_size, void* d_ws, size_t ws_size,
                              hipStream_t stream) {
  const int*   input_ids  = (const int*)d_in[0];
  const int*   attn_mask  = (const int*)d_in[1];
  const int*   token_type = (const int*)d_in[2];
  const float* word_emb   = (const float*)d_in[3];
  const float* pos_emb    = (const float*)d_in[4];
  const float* type_emb   = (const float*)d_in[5];
  const float* emb_ln_s   = (const float*)d_in[6];
  const float* emb_ln_b   = (const float*)d_in[7];
  const float* Wq = (const float*)d_in[8];
  const float* Wk = (const float*)d_in[9];
  const float* Wv = (const float*)d_in[10];
  const float* bq = (const float*)d_in[11];
  const float* bk = (const float*)d_in[12];
  const float* bv = (const float*)d_in[13];
  const float* Wo = (const float*)d_in[14];
  const float* bo = (const float*)d_in[15];
  const float* ln1_s = (const float*)d_in[16];
  const float* ln1_b = (const float*)d_in[17];
  const float* W1 = (const float*)d_in[18];
  const float* b1 = (const float*)d_in[19];
  const float* W2 = (const float*)d_in[20];
  const float* b2 = (const float*)d_in[21];
  const float* ln2_s = (const float*)d_in[22];
  const float* ln2_b = (const float*)d_in[23];
  const float* fc_w = (const float*)d_in[24];
  const float* fc_b = (const float*)d_in[25];
  float* out = (float*)d_out;

  const size_t SD = (size_t)S_LEN * DMODEL;
  float* wsf   = (float*)d_ws;
  int*   blk_i = (int*)d_ws;           // 256 ints
  float* dedup = wsf + 256;            // 256 floats
  float* qb    = wsf + 512;
  float* kbuf  = qb + SD;
  float* vbuf  = kbuf + SD;
  float* ctx   = vbuf + SD;
  float* tmp   = ctx + SD;
  float* xb    = tmp + SD;
  float* hb    = xb + SD;
  float* gsc   = hb + (size_t)S_LEN * FFDIM;   // 24*64*2048 floats

  blockmap_kernel<<<1, 1, 0, stream>>>(blk_i, dedup);
  embed_ln_kernel<<<S_LEN, 256, 0, stream>>>(input_ids, token_type, word_emb, pos_emb,
                                             type_emb, emb_ln_s, emb_ln_b, xb);

  for (int l = 0; l < NLAYER; ++l) {
    const float* Wq_l = Wq + (size_t)l * DMODEL * DMODEL;
    const float* Wk_l = Wk + (size_t)l * DMODEL * DMODEL;
    const float* Wv_l = Wv + (size_t)l * DMODEL * DMODEL;
    const float* Wo_l = Wo + (size_t)l * DMODEL * DMODEL;
    const float* W1_l = W1 + (size_t)l * DMODEL * FFDIM;
    const float* W2_l = W2 + (size_t)l * FFDIM * DMODEL;

    launch_gemm(xb, Wq_l, bq + l*DMODEL, qb,   S_LEN, DMODEL, DMODEL, 0, stream);
    launch_gemm(xb, Wk_l, bk + l*DMODEL, kbuf, S_LEN, DMODEL, DMODEL, 0, stream);
    launch_gemm(xb, Wv_l, bv + l*DMODEL, vbuf, S_LEN, DMODEL, DMODEL, 0, stream);

    sparse_attn_kernel<<<dim3(NB, NHEAD), 256, 0, stream>>>(qb, kbuf, vbuf, blk_i, dedup,
                                                            attn_mask, ctx);
    global_attn_kernel<<<dim3(2, NHEAD), 256, 0, stream>>>(qb, kbuf, vbuf, attn_mask,
                                                           gsc, ctx);

    launch_gemm(ctx, Wo_l, bo + l*DMODEL, tmp, S_LEN, DMODEL, DMODEL, 0, stream);
    resln_kernel<<<S_LEN, 256, 0, stream>>>(xb, tmp, ln1_s + l*DMODEL, ln1_b + l*DMODEL);

    launch_gemm(xb, W1_l, b1 + l*FFDIM, hb, S_LEN, FFDIM, DMODEL, 1, stream);
    launch_gemm(hb, W2_l, b2 + l*DMODEL, tmp, S_LEN, DMODEL, FFDIM, 0, stream);
    resln_kernel<<<S_LEN, 256, 0, stream>>>(xb, tmp, ln2_s + l*DMODEL, ln2_b + l*DMODEL);
  }

  launch_gemm(xb, fc_w, fc_b, out, S_LEN, VOCAB, DMODEL, 0, stream);
}

// Round 6
// 5304.900 us; speedup vs baseline: 3.9537x; 3.9537x over previous
//
#include <hip/hip_runtime.h>
#include <hip/hip_bf16.h>

// ---------------------------------------------------------------------------
// BigBird forward. Weights pre-transposed/converted to bf16 [N][K] once;
// GEMMs: A f32 split (hi+lo) x B bf16, 2-term MFMA. Attention: single-pass
// online softmax, split precision; global attn 4-way KV-partitioned + combine.
// ---------------------------------------------------------------------------

#define S_LEN 2048
#define DMODEL 768
#define FFDIM 3072
#define VOCAB 50358
#define VPAD  50432
#define NLAYER 12
#define NHEAD 12
#define NB 32
#define NKB 8
#define QKVN 2304

typedef __attribute__((ext_vector_type(8))) short bfrag8;
typedef __attribute__((ext_vector_type(8))) unsigned short us8;
typedef __attribute__((ext_vector_type(4))) float facc4;

__device__ __forceinline__ unsigned short f2bf(float f) {
  unsigned int u = __builtin_bit_cast(unsigned int, f);
  u += 0x7fffu + ((u >> 16) & 1u);
  return (unsigned short)(u >> 16);
}
__device__ __forceinline__ float bf2f(unsigned short h) {
  unsigned int u = ((unsigned int)h) << 16;
  return __builtin_bit_cast(float, u);
}

#define MFMA16(a, b, c) __builtin_amdgcn_mfma_f32_16x16x32_bf16((a), (b), (c), 0, 0, 0)
#define GLDS16(g, l) __builtin_amdgcn_global_load_lds( \
    (const __attribute__((address_space(1))) void*)(g), \
    (__attribute__((address_space(3))) void*)(l), 16, 0, 0)

// ---------------------------------------------------------------------------
// numpy RNG replication (validated: passes)
// ---------------------------------------------------------------------------
struct Pcg {
  unsigned long long hi, lo, inc_hi, inc_lo;
  int has32; unsigned int buf32;
};

__device__ __forceinline__ void pcg_step(Pcg& p) {
  const unsigned long long MH = 0x2360ed051fc65da4ull;
  const unsigned long long ML = 0x4385df649fccf645ull;
  unsigned long long rl = p.lo * ML;
  unsigned long long rh = __umul64hi(p.lo, ML) + p.lo * MH + p.hi * ML;
  unsigned long long nl = rl + p.inc_lo;
  unsigned long long nh = rh + p.inc_hi + (nl < rl ? 1ull : 0ull);
  p.lo = nl; p.hi = nh;
}
__device__ __forceinline__ unsigned long long pcg_next64(Pcg& p) {
  pcg_step(p);
  unsigned int rot = (unsigned int)(p.hi >> 58);
  unsigned long long x = p.hi ^ p.lo;
  return (x >> rot) | (x << ((64u - rot) & 63u));
}
__device__ __forceinline__ unsigned int pcg_next32(Pcg& p) {
  if (p.has32) { p.has32 = 0; return p.buf32; }
  unsigned long long n = pcg_next64(p);
  p.has32 = 1; p.buf32 = (unsigned int)(n >> 32);
  return (unsigned int)n;
}
__device__ __forceinline__ unsigned int lemire32(Pcg& p, unsigned int rng) {
  unsigned int rng_excl = rng + 1u;
  unsigned long long m = (unsigned long long)pcg_next32(p) * (unsigned long long)rng_excl;
  unsigned int leftover = (unsigned int)m;
  if (leftover < rng_excl) {
    unsigned int threshold = (0xffffffffu - rng) % rng_excl;
    while (leftover < threshold) {
      m = (unsigned long long)pcg_next32(p) * (unsigned long long)rng_excl;
      leftover = (unsigned int)m;
    }
  }
  return (unsigned int)(m >> 32);
}

__global__ void blockmap_kernel(int* __restrict__ blk_idx, float* __restrict__ dedup) {
  if (threadIdx.x != 0 || blockIdx.x != 0) return;
  unsigned int pool[4];
  unsigned int hc = 0x43b0d7e5u;
  auto ss_hash = [&hc](unsigned int val) {
    val ^= hc; hc *= 0x931e8875u; val *= hc; val ^= val >> 16; return val;
  };
  auto ss_mix = [](unsigned int x, unsigned int y) {
    unsigned int r = 0xca01f9ddu * x - 0x4973f715u * y;
    r ^= r >> 16; return r;
  };
  for (int i = 0; i < 4; ++i) pool[i] = ss_hash(0u);
  for (int s = 0; s < 4; ++s)
    for (int d = 0; d < 4; ++d)
      if (s != d) pool[d] = ss_mix(pool[d], ss_hash(pool[s]));
  unsigned int st32[8];
  unsigned int hb = 0x8b51f9ddu;
  for (int i = 0; i < 8; ++i) {
    unsigned int dv = pool[i & 3];
    dv ^= hb; hb *= 0x58f38dedu; dv *= hb; dv ^= dv >> 16;
    st32[i] = dv;
  }
  unsigned long long sd[4];
  for (int i = 0; i < 4; ++i)
    sd[i] = (unsigned long long)st32[2*i] | ((unsigned long long)st32[2*i+1] << 32);
  Pcg p;
  p.inc_hi = (sd[2] << 1) | (sd[3] >> 63);
  p.inc_lo = (sd[3] << 1) | 1ull;
  p.hi = 0ull; p.lo = 0ull;
  pcg_step(p);
  unsigned long long ol = p.lo;
  p.lo = ol + sd[1];
  p.hi = p.hi + sd[0] + (p.lo < ol ? 1ull : 0ull);
  pcg_step(p);
  p.has32 = 0; p.buf32 = 0;

  for (int i = 0; i < NB; ++i) {
    int lst[8];
    lst[0] = 0; lst[1] = NB - 1;
    lst[2] = (i > 0) ? i - 1 : 0;
    lst[3] = i;
    lst[4] = (i + 1 < NB - 1) ? i + 1 : NB - 1;
    bool excl[NB];
    for (int c = 0; c < NB; ++c) excl[c] = false;
    for (int j = 0; j < 5; ++j) excl[lst[j]] = true;
    int cand[NB], n = 0;
    for (int c = 0; c < NB; ++c) if (!excl[c]) cand[n++] = c;
    long long idx[3];
    unsigned long long hs[4] = {~0ull, ~0ull, ~0ull, ~0ull};
    for (int tI = 0; tI < 3; ++tI) {
      unsigned long long j = (unsigned long long)(n - 3 + tI);
      unsigned long long val = (unsigned long long)lemire32(p, (unsigned int)j);
      unsigned long long loc = val & 3ull;
      while (hs[loc] != ~0ull && hs[loc] != val) loc = (loc + 1ull) & 3ull;
      if (hs[loc] == ~0ull) { hs[loc] = val; idx[tI] = (long long)val; }
      else {
        loc = j & 3ull;
        while (hs[loc] != ~0ull) loc = (loc + 1ull) & 3ull;
        hs[loc] = j; idx[tI] = (long long)j;
      }
    }
    for (int fi = 2; fi >= 1; --fi) {
      int fj = (int)lemire32(p, (unsigned int)fi);
      long long tmpv = idx[fi]; idx[fi] = idx[fj]; idx[fj] = tmpv;
    }
    lst[5] = cand[idx[0]]; lst[6] = cand[idx[1]]; lst[7] = cand[idx[2]];

    unsigned int seen = 0u;
    for (int j = 0; j < 8; ++j) {
      blk_idx[i*8 + j] = lst[j];
      dedup[i*8 + j] = ((seen >> lst[j]) & 1u) ? 0.0f : 1.0f;
      seen |= (1u << lst[j]);
    }
  }
}

// ---------------------------------------------------------------------------
// Weight transpose+convert: src f32 [K][N] (+z*src_stride) -> dst bf16 [Npad][K]
// grid: (Npad/64, K/64, nmat). Scalar global reads (N may be unaligned).
// ---------------------------------------------------------------------------
__global__ __launch_bounds__(256) void tconv_kernel(
    const float* __restrict__ src, unsigned short* __restrict__ dst,
    int K, int N, size_t src_stride, size_t dst_stride) {
  __shared__ float tile[64][65];
  src += (size_t)blockIdx.z * src_stride;
  dst += (size_t)blockIdx.z * dst_stride;
  int n0 = blockIdx.x * 64, k0 = blockIdx.y * 64;
  int t = threadIdx.x;
  int tr = t >> 4, tc = (t & 15) * 4;
  for (int i = 0; i < 4; ++i) {
    int k = k0 + tr + i * 16;
    #pragma unroll
    for (int q2 = 0; q2 < 4; ++q2) {
      int n = n0 + tc + q2;
      tile[tr + i*16][tc + q2] = (n < N) ? src[(size_t)k * N + n] : 0.0f;
    }
  }
  __syncthreads();
  int wr_ = t >> 2, wc_ = (t & 3) * 16;
  us8 w0, w1;
  #pragma unroll
  for (int j = 0; j < 8; ++j) {
    w0[j] = f2bf(tile[wc_ + j][wr_]);
    w1[j] = f2bf(tile[wc_ + 8 + j][wr_]);
  }
  size_t b = (size_t)(n0 + wr_) * K + k0 + wc_;
  *reinterpret_cast<us8*>(dst + b) = w0;
  *reinterpret_cast<us8*>(dst + b + 8) = w1;
}

__global__ void bias_cat_kernel(const float* __restrict__ bq, const float* __restrict__ bk,
                                const float* __restrict__ bv, float* __restrict__ dst) {
  int l = blockIdx.x;
  for (int i = threadIdx.x; i < QKVN; i += blockDim.x) {
    float v = (i < 768) ? bq[l*768 + i] : (i < 1536) ? bk[l*768 + i - 768] : bv[l*768 + i - 1536];
    dst[l*QKVN + i] = v;
  }
}

// ---------------------------------------------------------------------------
// LayerNorm
// ---------------------------------------------------------------------------
__device__ __forceinline__ float block_sum256(float v, float* red) {
  for (int off = 32; off > 0; off >>= 1) v += __shfl_down(v, off);
  int wv = threadIdx.x >> 6;
  if ((threadIdx.x & 63) == 0) red[wv] = v;
  __syncthreads();
  float r = red[0] + red[1] + red[2] + red[3];
  __syncthreads();
  return r;
}

__global__ void embed_ln_kernel(const int* __restrict__ ids, const int* __restrict__ tts,
                                const float* __restrict__ we, const float* __restrict__ pe,
                                const float* __restrict__ te, const float* __restrict__ lns,
                                const float* __restrict__ lnb, float* __restrict__ x) {
  __shared__ float red[4];
  int row = blockIdx.x, t = threadIdx.x;
  int id = ids[row], ty = tts[row];
  float e[3]; float s = 0.0f;
  for (int j = 0; j < 3; ++j) {
    int d = t + 256*j;
    e[j] = we[(size_t)id*DMODEL + d] + pe[(size_t)row*DMODEL + d] + te[(size_t)ty*DMODEL + d];
    s += e[j];
  }
  float mean = block_sum256(s, red) * (1.0f/768.0f);
  float vs = 0.0f;
  for (int j = 0; j < 3; ++j) { float dd = e[j] - mean; vs += dd*dd; }
  float var = block_sum256(vs, red) * (1.0f/768.0f);
  float inv = rsqrtf(var + 1e-12f);
  for (int j = 0; j < 3; ++j) {
    int d = t + 256*j;
    x[(size_t)row*DMODEL + d] = (e[j] - mean) * inv * lns[d] + lnb[d];
  }
}

__global__ void resln_kernel(float* __restrict__ x, const float* __restrict__ a,
                             const float* __restrict__ lns, const float* __restrict__ lnb) {
  __shared__ float red[4];
  int row = blockIdx.x, t = threadIdx.x;
  float e[3]; float s = 0.0f;
  for (int j = 0; j < 3; ++j) {
    int d = t + 256*j;
    e[j] = x[(size_t)row*DMODEL + d] + a[(size_t)row*DMODEL + d];
    s += e[j];
  }
  float mean = block_sum256(s, red) * (1.0f/768.0f);
  float vs = 0.0f;
  for (int j = 0; j < 3; ++j) { float dd = e[j] - mean; vs += dd*dd; }
  float var = block_sum256(vs, red) * (1.0f/768.0f);
  float inv = rsqrtf(var + 1e-12f);
  for (int j = 0; j < 3; ++j) {
    int d = t + 256*j;
    x[(size_t)row*DMODEL + d] = (e[j] - mean) * inv * lns[d] + lnb[d];
  }
}

// ---------------------------------------------------------------------------
// GEMM v2: C[M,Nreal] = act(A[M,K] @ Bt^T + bias), Bt = bf16 [Npad][K].
// A split (hi+lo) on the fly; 2 MFMAs/pair. B staged via global_load_lds.
// ---------------------------------------------------------------------------
__global__ __launch_bounds__(256) void gemm2_kernel(
    const float* __restrict__ A, const unsigned short* __restrict__ Bt,
    const float* __restrict__ bias, float* __restrict__ C,
    int M, int Npad, int K, int Nreal, int act) {
  __shared__ alignas(16) unsigned short Ah[128][32];
  __shared__ alignas(16) unsigned short Al[128][32];
  __shared__ alignas(16) unsigned short Bs[128][32];
  int t = threadIdx.x;
  int n0 = blockIdx.x * 128, m0 = blockIdx.y * 128;
  int wave = t >> 6, lane = t & 63, l16 = lane & 15, lk = lane >> 4;
  int wr = wave >> 1, wc = wave & 1;
  facc4 acc[4][4];
  for (int mi = 0; mi < 4; ++mi)
    for (int ni = 0; ni < 4; ++ni)
      acc[mi][ni] = (facc4){0.f, 0.f, 0.f, 0.f};
  const int arow = t >> 3, acol = (t & 7) * 4;
  const unsigned short* browp = Bt + (size_t)(n0 + wave*32 + (lane >> 2)) * K + (lane & 3) * 8;
  unsigned short* ldsb0 = &Bs[wave*32][0];
  unsigned short* ldsb1 = &Bs[wave*32 + 16][0];

  for (int k0 = 0; k0 < K; k0 += 32) {
    GLDS16(browp + k0, ldsb0);
    GLDS16(browp + (size_t)16 * K + k0, ldsb1);
    #pragma unroll
    for (int j = 0; j < 4; ++j) {
      const float4 vv = *reinterpret_cast<const float4*>(
          A + (size_t)(m0 + arow + 32*j) * K + k0 + acol);
      ushort4 h4, l4;
      h4.x = f2bf(vv.x); l4.x = f2bf(vv.x - bf2f(h4.x));
      h4.y = f2bf(vv.y); l4.y = f2bf(vv.y - bf2f(h4.y));
      h4.z = f2bf(vv.z); l4.z = f2bf(vv.z - bf2f(h4.z));
      h4.w = f2bf(vv.w); l4.w = f2bf(vv.w - bf2f(h4.w));
      *reinterpret_cast<ushort4*>(&Ah[arow + 32*j][acol]) = h4;
      *reinterpret_cast<ushort4*>(&Al[arow + 32*j][acol]) = l4;
    }
    __syncthreads();
    bfrag8 afh[4], afl[4], bf[4];
    #pragma unroll
    for (int mi = 0; mi < 4; ++mi) {
      afh[mi] = *reinterpret_cast<const bfrag8*>(&Ah[wr*64 + mi*16 + l16][lk*8]);
      afl[mi] = *reinterpret_cast<const bfrag8*>(&Al[wr*64 + mi*16 + l16][lk*8]);
    }
    #pragma unroll
    for (int ni = 0; ni < 4; ++ni)
      bf[ni] = *reinterpret_cast<const bfrag8*>(&Bs[wc*64 + ni*16 + l16][lk*8]);
    #pragma unroll
    for (int mi = 0; mi < 4; ++mi)
      #pragma unroll
      for (int ni = 0; ni < 4; ++ni) {
        acc[mi][ni] = MFMA16(afh[mi], bf[ni], acc[mi][ni]);
        acc[mi][ni] = MFMA16(afl[mi], bf[ni], acc[mi][ni]);
      }
    __syncthreads();
  }

  for (int mi = 0; mi < 4; ++mi)
    for (int ni = 0; ni < 4; ++ni) {
      int col = n0 + wc*64 + ni*16 + l16;
      if (col >= Nreal) continue;
      float bv = bias[col];
      for (int r = 0; r < 4; ++r) {
        int row = m0 + wr*64 + mi*16 + lk*4 + r;
        float val = acc[mi][ni][r] + bv;
        if (act == 1) {
          float xx = val;
          val = 0.5f * xx * (1.0f + tanhf(0.7978845608028654f * (xx + 0.044715f * xx * xx * xx)));
        }
        C[(size_t)row * Nreal + col] = val;
      }
    }
}

// ---------------------------------------------------------------------------
// Attention staging (split f32 -> hi/lo bf16 LDS), direct and transposed
// ---------------------------------------------------------------------------
__device__ __forceinline__ void stage_split(unsigned short (*dsth)[64], unsigned short (*dstl)[64],
                                            const float* __restrict__ src, int ld, int t) {
  int row = t >> 2, colb = (t & 3) * 16;
  const float* sp = src + (size_t)row * ld + colb;
  #pragma unroll
  for (int j = 0; j < 4; ++j) {
    float4 vv = *reinterpret_cast<const float4*>(sp + j*4);
    ushort4 h4, l4;
    h4.x = f2bf(vv.x); l4.x = f2bf(vv.x - bf2f(h4.x));
    h4.y = f2bf(vv.y); l4.y = f2bf(vv.y - bf2f(h4.y));
    h4.z = f2bf(vv.z); l4.z = f2bf(vv.z - bf2f(h4.z));
    h4.w = f2bf(vv.w); l4.w = f2bf(vv.w - bf2f(h4.w));
    *reinterpret_cast<ushort4*>(&dsth[row][colb + j*4]) = h4;
    *reinterpret_cast<ushort4*>(&dstl[row][colb + j*4]) = l4;
  }
}
__device__ __forceinline__ void stage_splitT(unsigned short (*dsth)[64], unsigned short (*dstl)[64],
                                             const float* __restrict__ src, int ld, int t) {
  int row = t >> 2, colb = (t & 3) * 16;
  const float* sp = src + (size_t)row * ld + colb;
  #pragma unroll
  for (int j = 0; j < 4; ++j) {
    float4 vv = *reinterpret_cast<const float4*>(sp + j*4);
    int c = colb + j*4;
    unsigned short h;
    h = f2bf(vv.x); dsth[c+0][row] = h; dstl[c+0][row] = f2bf(vv.x - bf2f(h));
    h = f2bf(vv.y); dsth[c+1][row] = h; dstl[c+1][row] = f2bf(vv.y - bf2f(h));
    h = f2bf(vv.z); dsth[c+2][row] = h; dstl[c+2][row] = f2bf(vv.z - bf2f(h));
    h = f2bf(vv.w); dsth[c+3][row] = h; dstl[c+3][row] = f2bf(vv.w - bf2f(h));
  }
}

__device__ __forceinline__ void unpack_pair(int4 u0, int4 u1, bfrag8& hi, bfrag8& lo) {
  int a[8] = {u0.x, u0.y, u0.z, u0.w, u1.x, u1.y, u1.z, u1.w};
  #pragma unroll
  for (int j = 0; j < 8; ++j) {
    hi[j] = (short)((unsigned)a[j] & 0xffffu);
    lo[j] = (short)((unsigned)a[j] >> 16);
  }
}

// ---------------------------------------------------------------------------
// Attention, single-pass online softmax. GLOBAL=0: sparse, qi in [1,30],
// blocks from blk_idx. GLOBAL=1: q-block 0/31, kv-partition blockIdx.z (8 kb),
// writes unnormalized partials (o, m, l) to workspace.
// ---------------------------------------------------------------------------
template<int GLOBAL>
__global__ __launch_bounds__(256) void attn_kernel(
    const float* __restrict__ qkv, const int* __restrict__ blk_idx,
    const float* __restrict__ dedup, const int* __restrict__ amask,
    float* __restrict__ ctx, float* __restrict__ go,
    float* __restrict__ gm, float* __restrict__ gl) {
  __shared__ alignas(16) unsigned short Qh[64][64], Ql[64][64];
  __shared__ alignas(16) unsigned short KVh[64][64], KVl[64][64];
  __shared__ alignas(16) unsigned int Pt[64][68];
  int h = blockIdx.y;
  int qi = GLOBAL ? (blockIdx.x ? (NB - 1) : 0) : ((int)blockIdx.x + 1);
  int part = GLOBAL ? (int)blockIdx.z : 0;
  int t = threadIdx.x, wave = t >> 6, lane = t & 63, l16 = lane & 15, lk = lane >> 4;

  stage_split(Qh, Ql, qkv + (size_t)(qi*64)*QKVN + h*64, QKVN, t);
  __syncthreads();
  const bfrag8 qh0 = *reinterpret_cast<const bfrag8*>(&Qh[wave*16 + l16][lk*8]);
  const bfrag8 qh1 = *reinterpret_cast<const bfrag8*>(&Qh[wave*16 + l16][32 + lk*8]);
  const bfrag8 ql0 = *reinterpret_cast<const bfrag8*>(&Ql[wave*16 + l16][lk*8]);
  const bfrag8 ql1 = *reinterpret_cast<const bfrag8*>(&Ql[wave*16 + l16][32 + lk*8]);

  float mrow[4] = {-3.0e38f, -3.0e38f, -3.0e38f, -3.0e38f};
  float lrow[4] = {0.f, 0.f, 0.f, 0.f};
  facc4 o[4];
  #pragma unroll
  for (int ni = 0; ni < 4; ++ni) o[ni] = (facc4){0.f, 0.f, 0.f, 0.f};

  for (int kb = 0; kb < 8; ++kb) {
    int b; float dd;
    if (GLOBAL) { b = part*8 + kb; dd = 1.0f; }
    else { b = blk_idx[qi*NKB + kb]; dd = dedup[qi*NKB + kb]; }
    __syncthreads();
    stage_split(KVh, KVl, qkv + (size_t)(b*64)*QKVN + DMODEL + h*64, QKVN, t);
    __syncthreads();
    float s[4][4];
    #pragma unroll
    for (int ni = 0; ni < 4; ++ni) {
      bfrag8 kh0 = *reinterpret_cast<const bfrag8*>(&KVh[ni*16 + l16][lk*8]);
      bfrag8 kl0 = *reinterpret_cast<const bfrag8*>(&KVl[ni*16 + l16][lk*8]);
      bfrag8 kh1 = *reinterpret_cast<const bfrag8*>(&KVh[ni*16 + l16][32 + lk*8]);
      bfrag8 kl1 = *reinterpret_cast<const bfrag8*>(&KVl[ni*16 + l16][32 + lk*8]);
      facc4 sa = (facc4){0.f, 0.f, 0.f, 0.f};
      sa = MFMA16(qh0, kh0, sa); sa = MFMA16(qh0, kl0, sa); sa = MFMA16(ql0, kh0, sa);
      sa = MFMA16(qh1, kh1, sa); sa = MFMA16(qh1, kl1, sa); sa = MFMA16(ql1, kh1, sa);
      int colk = ni*16 + l16;
      float mk = (float)amask[b*64 + colk] * dd;
      float addm = (1.0f - mk) * (-1.0e9f);
      #pragma unroll
      for (int r = 0; r < 4; ++r) s[ni][r] = sa[r] * 0.125f + addm;
    }
    float pexp[4][4];
    #pragma unroll
    for (int r = 0; r < 4; ++r) {
      float tm = fmaxf(fmaxf(s[0][r], s[1][r]), fmaxf(s[2][r], s[3][r]));
      tm = fmaxf(tm, __shfl_xor(tm, 1));
      tm = fmaxf(tm, __shfl_xor(tm, 2));
      tm = fmaxf(tm, __shfl_xor(tm, 4));
      tm = fmaxf(tm, __shfl_xor(tm, 8));
      float mn = fmaxf(mrow[r], tm);
      float f = expf(mrow[r] - mn);
      #pragma unroll
      for (int ni = 0; ni < 4; ++ni) o[ni][r] *= f;
      float ps = 0.0f;
      #pragma unroll
      for (int ni = 0; ni < 4; ++ni) { pexp[ni][r] = expf(s[ni][r] - mn); ps += pexp[ni][r]; }
      ps += __shfl_xor(ps, 1);
      ps += __shfl_xor(ps, 2);
      ps += __shfl_xor(ps, 4);
      ps += __shfl_xor(ps, 8);
      lrow[r] = lrow[r] * f + ps;
      mrow[r] = mn;
    }
    #pragma unroll
    for (int ni = 0; ni < 4; ++ni)
      #pragma unroll
      for (int r = 0; r < 4; ++r) {
        float pv = pexp[ni][r];
        unsigned short hi = f2bf(pv);
        unsigned short lo = f2bf(pv - bf2f(hi));
        Pt[wave*16 + lk*4 + r][ni*16 + l16] = (unsigned)hi | ((unsigned)lo << 16);
      }
    __syncthreads();
    stage_splitT(KVh, KVl, qkv + (size_t)(b*64)*QKVN + 2*DMODEL + h*64, QKVN, t);
    __syncthreads();
    #pragma unroll
    for (int kc = 0; kc < 2; ++kc) {
      int4 u0 = *reinterpret_cast<const int4*>(&Pt[wave*16 + l16][kc*32 + lk*8]);
      int4 u1 = *reinterpret_cast<const int4*>(&Pt[wave*16 + l16][kc*32 + lk*8 + 4]);
      bfrag8 ph, pl;
      unpack_pair(u0, u1, ph, pl);
      #pragma unroll
      for (int ni = 0; ni < 4; ++ni) {
        bfrag8 vh = *reinterpret_cast<const bfrag8*>(&KVh[ni*16 + l16][kc*32 + lk*8]);
        bfrag8 vl = *reinterpret_cast<const bfrag8*>(&KVl[ni*16 + l16][kc*32 + lk*8]);
        o[ni] = MFMA16(ph, vh, o[ni]);
        o[ni] = MFMA16(ph, vl, o[ni]);
        o[ni] = MFMA16(pl, vh, o[ni]);
      }
    }
  }

  if (!GLOBAL) {
    float invl[4];
    #pragma unroll
    for (int r = 0; r < 4; ++r) invl[r] = 1.0f / lrow[r];
    #pragma unroll
    for (int ni = 0; ni < 4; ++ni)
      #pragma unroll
      for (int r = 0; r < 4; ++r) {
        int row = qi*64 + wave*16 + lk*4 + r;
        int col = h*64 + ni*16 + l16;
        ctx[(size_t)row*DMODEL + col] = o[ni][r] * invl[r];
      }
  } else {
    int pidx = ((int)blockIdx.x * NHEAD + h) * 4 + part;
    float* gob = go + (size_t)pidx * 64 * 64;
    #pragma unroll
    for (int ni = 0; ni < 4; ++ni)
      #pragma unroll
      for (int r = 0; r < 4; ++r)
        gob[(wave*16 + lk*4 + r) * 64 + ni*16 + l16] = o[ni][r];
    if (l16 == 0) {
      #pragma unroll
      for (int r = 0; r < 4; ++r) {
        int row = wave*16 + lk*4 + r;
        gm[pidx*64 + row] = mrow[r];
        gl[pidx*64 + row] = lrow[r];
      }
    }
  }
}

__global__ __launch_bounds__(256) void gattn_comb_kernel(
    const float* __restrict__ go, const float* __restrict__ gm,
    const float* __restrict__ gl, float* __restrict__ ctx) {
  int g = blockIdx.x, h = blockIdx.y;
  int t = threadIdx.x;
  int row = t >> 2, cseg = (t & 3) * 16;
  int base = (g * NHEAD + h) * 4;
  float m = -3.0e38f;
  for (int p = 0; p < 4; ++p) m = fmaxf(m, gm[(base + p)*64 + row]);
  float w[4]; float l = 0.0f;
  for (int p = 0; p < 4; ++p) {
    w[p] = expf(gm[(base + p)*64 + row] - m);
    l += gl[(base + p)*64 + row] * w[p];
  }
  float inv = 1.0f / l;
  int qrow = (g ? (NB - 1) * 64 : 0) + row;
  for (int c = 0; c < 16; ++c) {
    float acc = 0.0f;
    for (int p = 0; p < 4; ++p)
      acc += go[((size_t)(base + p)*64 + row)*64 + cseg + c] * w[p];
    ctx[(size_t)qrow*DMODEL + h*64 + cseg + c] = acc * inv;
  }
}

// ---------------------------------------------------------------------------
// Launch
// ---------------------------------------------------------------------------
extern "C" void kernel_launch(void* const* d_in, const int* in_sizes, int n_in,
                              void* d_out, int out_size, void* d_ws, size_t ws_size,
                              hipStream_t stream) {
  const int*   input_ids  = (const int*)d_in[0];
  const int*   attn_mask  = (const int*)d_in[1];
  const int*   token_type = (const int*)d_in[2];
  const float* word_emb   = (const float*)d_in[3];
  const float* pos_emb    = (const float*)d_in[4];
  const float* type_emb   = (const float*)d_in[5];
  const float* emb_ln_s   = (const float*)d_in[6];
  const float* emb_ln_b   = (const float*)d_in[7];
  const float* Wq = (const float*)d_in[8];
  const float* Wk = (const float*)d_in[9];
  const float* Wv = (const float*)d_in[10];
  const float* bq = (const float*)d_in[11];
  const float* bk = (const float*)d_in[12];
  const float* bv = (const float*)d_in[13];
  const float* Wo = (const float*)d_in[14];
  const float* bo = (const float*)d_in[15];
  const float* ln1_s = (const float*)d_in[16];
  const float* ln1_b = (const float*)d_in[17];
  const float* W1 = (const float*)d_in[18];
  const float* b1 = (const float*)d_in[19];
  const float* W2 = (const float*)d_in[20];
  const float* b2 = (const float*)d_in[21];
  const float* ln2_s = (const float*)d_in[22];
  const float* ln2_b = (const float*)d_in[23];
  const float* fc_w = (const float*)d_in[24];
  const float* fc_b = (const float*)d_in[25];
  float* out = (float*)d_out;

  unsigned char* base = (unsigned char*)d_ws;
  size_t off = 0;
  auto carve = [&](size_t bytes) -> void* {
    void* p = base + off;
    off = (off + bytes + 255) & ~(size_t)255;
    return p;
  };
  int*   blk_i = (int*)carve(256 * 4);
  float* dedup = (float*)carve(256 * 4);
  float* bqkv  = (float*)carve((size_t)NLAYER * QKVN * 4);
  float* qkv   = (float*)carve((size_t)S_LEN * QKVN * 4);
  float* ctx   = (float*)carve((size_t)S_LEN * DMODEL * 4);
  float* tmp   = (float*)carve((size_t)S_LEN * DMODEL * 4);
  float* xb    = (float*)carve((size_t)S_LEN * DMODEL * 4);
  float* hb    = (float*)carve((size_t)S_LEN * FFDIM * 4);
  float* go    = (float*)carve((size_t)2 * NHEAD * 4 * 64 * 64 * 4);
  float* gm    = (float*)carve((size_t)2 * NHEAD * 4 * 64 * 4);
  float* gl    = (float*)carve((size_t)2 * NHEAD * 4 * 64 * 4);
  unsigned short* qkvT = (unsigned short*)carve((size_t)NLAYER * QKVN * DMODEL * 2);
  unsigned short* woT  = (unsigned short*)carve((size_t)NLAYER * DMODEL * DMODEL * 2);
  unsigned short* w1T  = (unsigned short*)carve((size_t)NLAYER * FFDIM * DMODEL * 2);
  unsigned short* w2T  = (unsigned short*)carve((size_t)NLAYER * DMODEL * FFDIM * 2);
  unsigned short* fcT  = (unsigned short*)carve((size_t)VPAD * DMODEL * 2);

  blockmap_kernel<<<1, 1, 0, stream>>>(blk_i, dedup);

  // weight preprocessing: transpose+convert to bf16 [N][K]
  const size_t DD = (size_t)DMODEL * DMODEL;
  dim3 g768(12, 12, NLAYER);
  tconv_kernel<<<g768, 256, 0, stream>>>(Wq, qkvT + 0,            DMODEL, DMODEL, DD, (size_t)QKVN * DMODEL);
  tconv_kernel<<<g768, 256, 0, stream>>>(Wk, qkvT + 768 * DMODEL, DMODEL, DMODEL, DD, (size_t)QKVN * DMODEL);
  tconv_kernel<<<g768, 256, 0, stream>>>(Wv, qkvT + 1536 * DMODEL,DMODEL, DMODEL, DD, (size_t)QKVN * DMODEL);
  tconv_kernel<<<g768, 256, 0, stream>>>(Wo, woT, DMODEL, DMODEL, DD, DD);
  tconv_kernel<<<dim3(48, 12, NLAYER), 256, 0, stream>>>(W1, w1T, DMODEL, FFDIM, (size_t)DMODEL * FFDIM, (size_t)FFDIM * DMODEL);
  tconv_kernel<<<dim3(12, 48, NLAYER), 256, 0, stream>>>(W2, w2T, FFDIM, DMODEL, (size_t)FFDIM * DMODEL, (size_t)DMODEL * FFDIM);
  tconv_kernel<<<dim3(VPAD / 64, 12, 1), 256, 0, stream>>>(fc_w, fcT, DMODEL, VOCAB, 0, 0);
  bias_cat_kernel<<<NLAYER, 256, 0, stream>>>(bq, bk, bv, bqkv);

  embed_ln_kernel<<<S_LEN, 256, 0, stream>>>(input_ids, token_type, word_emb, pos_emb,
                                             type_emb, emb_ln_s, emb_ln_b, xb);

  for (int l = 0; l < NLAYER; ++l) {
    gemm2_kernel<<<dim3(QKVN/128, 16), 256, 0, stream>>>(
        xb, qkvT + (size_t)l * QKVN * DMODEL, bqkv + (size_t)l * QKVN, qkv,
        S_LEN, QKVN, DMODEL, QKVN, 0);

    attn_kernel<0><<<dim3(30, NHEAD), 256, 0, stream>>>(qkv, blk_i, dedup, attn_mask,
                                                        ctx, nullptr, nullptr, nullptr);
    attn_kernel<1><<<dim3(2, NHEAD, 4), 256, 0, stream>>>(qkv, nullptr, nullptr, attn_mask,
                                                          nullptr, go, gm, gl);
    gattn_comb_kernel<<<dim3(2, NHEAD), 256, 0, stream>>>(go, gm, gl, ctx);

    gemm2_kernel<<<dim3(6, 16), 256, 0, stream>>>(
        ctx, woT + (size_t)l * DD, bo + (size_t)l * DMODEL, tmp,
        S_LEN, DMODEL, DMODEL, DMODEL, 0);
    resln_kernel<<<S_LEN, 256, 0, stream>>>(xb, tmp, ln1_s + l*DMODEL, ln1_b + l*DMODEL);

    gemm2_kernel<<<dim3(24, 16), 256, 0, stream>>>(
        xb, w1T + (size_t)l * FFDIM * DMODEL, b1 + (size_t)l * FFDIM, hb,
        S_LEN, FFDIM, DMODEL, FFDIM, 1);
    gemm2_kernel<<<dim3(6, 16), 256, 0, stream>>>(
        hb, w2T + (size_t)l * DMODEL * FFDIM, b2 + (size_t)l * DMODEL, tmp,
        S_LEN, DMODEL, FFDIM, DMODEL, 0);
    resln_kernel<<<S_LEN, 256, 0, stream>>>(xb, tmp, ln2_s + l*DMODEL, ln2_b + l*DMODEL);
  }

  gemm2_kernel<<<dim3(VPAD/128, 16), 256, 0, stream>>>(
      xb, fcT, fc_b, out, S_LEN, VPAD, DMODEL, VOCAB, 0);
}